// Round 17
// baseline (183.083 us; speedup 1.0000x reference)
//
#include <hip/hip_runtime.h>
#include <hip/hip_cooperative_groups.h>
#include <math.h>

#define B 32
#define H 8
#define N 512
#define NBLK 256   // cooperative blocks (1 per CU)
#define TPB 512
#define RPB 64     // G rows per cooperative block
// d_out tail scratch (floats), consumed before k_final overwrites:
#define OFF_PA   8388608             // B*N*8 transposed partials, buffer A
#define OFF_PB   (OFF_PA + 131072)   // buffer B
#define OFF_C0A  (OFF_PB + 131072)   // B*8*8 transposed c0 partials
#define OFF_C0B  (OFF_C0A + 2048)

typedef float f32x4 __attribute__((ext_vector_type(4)));  // ok for nontemporal builtins

// Cross-block data moves through relaxed agent-scope atomics (sc-bit,
// coherence-point accesses). No fences -> no L2 writeback/invalidate storms.
__device__ __forceinline__ float2 atomLoad2(const float* p) {
    unsigned long long u = __hip_atomic_load(
        reinterpret_cast<const unsigned long long*>(p),
        __ATOMIC_RELAXED, __HIP_MEMORY_SCOPE_AGENT);
    union { unsigned long long u; float2 f; } cvt; cvt.u = u;
    return cvt.f;
}
__device__ __forceinline__ void atomStore(float* p, float v) {
    __hip_atomic_store(p, v, __ATOMIC_RELAXED, __HIP_MEMORY_SCOPE_AGENT);
}

// 8-block (one b-group) barrier. __syncthreads() drains vmcnt for every wave,
// so all sc-bit data stores are globally visible before the signal.
__device__ __forceinline__ void group_barrier(int* cnt, int target) {
    __syncthreads();
    if (threadIdx.x == 0) {
        __hip_atomic_fetch_add(cnt, 1, __ATOMIC_RELAXED, __HIP_MEMORY_SCOPE_AGENT);
        while (__hip_atomic_load(cnt, __ATOMIC_RELAXED, __HIP_MEMORY_SCOPE_AGENT) < target)
            __builtin_amdgcn_s_sleep(1);
    }
    __syncthreads();
}

// Zero the group-barrier counters (ws is poisoned 0xAA before timing).
__global__ void k_zero(int* __restrict__ counters) {
    counters[threadIdx.x] = 0;
}

// Fused build + 5x(row,col) normalization, 1 block/CU (proven round-15 structure).
// Build phase: 8 sequential iterations, each with TWO interleaved row-chunks
// (16 independent float4 loads in flight, ~100 VGPR). NO __launch_bounds__ min:
// at 1 block/CU the allocator has ~256 VGPR headroom -> no spill (round-13's
// spill came from the launch_bounds(,2) 128-VGPR cap, not the depth itself).
// Sum order over h matches k_build exactly -> bitwise-identical G.
__global__ __launch_bounds__(TPB) void k_coopb(const float* __restrict__ in,
                                               float* __restrict__ partA,
                                               float* __restrict__ partB,
                                               float* __restrict__ c0pA,
                                               float* __restrict__ c0pB,
                                               float* __restrict__ rv,
                                               float* __restrict__ r0v,
                                               float* __restrict__ cv,
                                               float* __restrict__ c0v,
                                               int* __restrict__ counters) {
    __shared__ float Gs[RPB][N];   // 128 KB
    __shared__ float E0g[N];       // exp(x[b, g, 0, :]) (head h=g row-0 slice)
    __shared__ float vec[N];       // c values (row phase)
    __shared__ float EcS[H][RPB];  // exp(x[b, h, rbase+il, 0])
    __shared__ float rloc[RPB];
    __shared__ float c0rec[H];
    __shared__ float r0loc_s;

    const int blk = blockIdx.x;
    const int b = blk >> 3;
    const int g = blk & 7;
    const int rbase = g * RPB;
    const bool owner = (g == 0);
    const int tid = threadIdx.x;
    const int w = tid >> 6, lane = tid & 63;
    int* cnt = counters + b * 16;

    // ---- build phase: G rows straight from input into LDS (16-deep MLP) ----
    const int il4 = tid >> 7;      // 0..3
    const int j4 = tid & 127;      // float4 column index
    const size_t inb = (size_t)b * H * N * N;
    for (int c = 0; c < 8; ++c) {
        const int ilA = c * 8 + il4;
        const int ilB = ilA + 4;
        const float* rbA = in + inb + (size_t)(rbase + ilA) * N + j4 * 4;
        const float* rbB = in + inb + (size_t)(rbase + ilB) * N + j4 * 4;
        float4 xa[8], xb[8];
#pragma unroll
        for (int h = 0; h < H; ++h) {
            xa[h] = *reinterpret_cast<const float4*>(rbA + (size_t)h * N * N);
            xb[h] = *reinterpret_cast<const float4*>(rbB + (size_t)h * N * N);
        }
        float4 accA = make_float4(0.f, 0.f, 0.f, 0.f);
        float4 accB = make_float4(0.f, 0.f, 0.f, 0.f);
#pragma unroll
        for (int h = 0; h < H; ++h) {
            float4 ea, eb;
            ea.x = __expf(xa[h].x); ea.y = __expf(xa[h].y);
            ea.z = __expf(xa[h].z); ea.w = __expf(xa[h].w);
            eb.x = __expf(xb[h].x); eb.y = __expf(xb[h].y);
            eb.z = __expf(xb[h].z); eb.w = __expf(xb[h].w);
            accA.x += ea.x; accA.y += ea.y; accA.z += ea.z; accA.w += ea.w;
            accB.x += eb.x; accB.y += eb.y; accB.z += eb.z; accB.w += eb.w;
            if (j4 == 0) { EcS[h][ilA] = ea.x; EcS[h][ilB] = eb.x; }
        }
        *reinterpret_cast<float4*>(&Gs[ilA][j4 * 4]) = accA;
        *reinterpret_cast<float4*>(&Gs[ilB][j4 * 4]) = accB;
    }
    if (tid < 128) {   // E0g: exp of row (b, g, 0, :)
        const float4 xr = *reinterpret_cast<const float4*>(in + inb + (size_t)g * N * N + tid * 4);
        E0g[tid * 4 + 0] = __expf(xr.x);
        E0g[tid * 4 + 1] = __expf(xr.y);
        E0g[tid * 4 + 2] = __expf(xr.z);
        E0g[tid * 4 + 3] = __expf(xr.w);
    }
    __syncthreads();
    const float E00g = E0g[0];     // exp(x[b, g, 0, 0])

    for (int it = 0; it < 5; ++it) {
        // ---------- recompute c factors from transposed partials ----------
        if (it == 0) {
            vec[tid] = (tid == 0) ? 0.0f : 1.0f;  // c = 1; j=0 handled via c0 term
            if (tid < H) c0rec[tid] = 1.0f;
        } else {
            const float* pr = (it & 1) ? partB : partA;
            pr += ((size_t)b * N + tid) * 8;
            float cs = 0.0f;
#pragma unroll
            for (int k = 0; k < 4; ++k) {
                float2 d = atomLoad2(pr + 2 * k);
                cs += d.x + d.y;
            }
            vec[tid] = (tid == 0) ? 0.0f : 1.0f / cs;
            if (tid < H) {
                const float* qr = (it & 1) ? c0pB : c0pA;
                qr += (b * 8 + tid) * 8;
                float s = 0.0f;
#pragma unroll
                for (int k = 0; k < 4; ++k) {
                    float2 d = atomLoad2(qr + 2 * k);
                    s += d.x + d.y;
                }
                c0rec[tid] = 1.0f / s;
            }
        }
        __syncthreads();
        float cj[8];
#pragma unroll
        for (int k = 0; k < 8; ++k) cj[k] = vec[lane + 64 * k];
#pragma unroll
        for (int r8 = 0; r8 < 8; ++r8) {
            const int il = w * 8 + r8;
            float pacc = 0.0f;
#pragma unroll
            for (int k = 0; k < 8; ++k) pacc += Gs[il][lane + 64 * k] * cj[k];
#pragma unroll
            for (int s = 32; s > 0; s >>= 1) pacc += __shfl_down(pacc, s, 64);
            if (lane == 0) {
                float s2 = pacc;
#pragma unroll
                for (int h = 0; h < H; ++h) s2 += EcS[h][il] * c0rec[h];
                float rva = 1.0f / s2;
                rloc[il] = rva;                 // garbage for owner il=0, masked below
                if (it == 4) rv[b * N + rbase + il] = rva;
            }
        }
        if (w == g) {   // r0 for head h=g
            float pacc = 0.0f;
#pragma unroll
            for (int k = 0; k < 8; ++k) pacc += E0g[lane + 64 * k] * cj[k];
#pragma unroll
            for (int s = 32; s > 0; s >>= 1) pacc += __shfl_down(pacc, s, 64);
            if (lane == 0) {
                float v = 1.0f / (pacc + E00g * c0rec[g]);
                r0loc_s = v;
                if (it == 4) r0v[b * H + g] = v;
            }
        }
        __syncthreads();
        // ---------- col phase: partial column sums (transposed store) ----------
        {
            float* pw = ((it + 1) & 1) ? partB : partA;
            float* qw = ((it + 1) & 1) ? c0pB : c0pA;
            const float r0l = r0loc_s;
            float acc2 = 0.0f;
            const int il0 = owner ? 1 : 0;  // global row 0 handled via E0 terms
#pragma unroll 8
            for (int il = il0; il < RPB; ++il) acc2 += Gs[il][tid] * rloc[il];
            acc2 += E0g[tid] * r0l;         // head g's i=0 contribution
            atomStore(&pw[((size_t)b * N + tid) * 8 + g], acc2);
            float q = EcS[w][lane] * ((owner && lane == 0) ? 0.0f : rloc[lane]);
            if (w == g && lane == 0) q += E00g * r0l;
#pragma unroll
            for (int s = 32; s > 0; s >>= 1) q += __shfl_down(q, s, 64);
            if (lane == 0) atomStore(&qw[(b * 8 + w) * 8 + g], q);
        }
        group_barrier(cnt, (it + 1) * 8);
    }
    // ---- finalize c factors (block g==0 of each b) ----
    if (owner) {
        const float* pr = partB + ((size_t)b * N + tid) * 8;   // (4+1)&1 == 1
        float cs = 0.0f;
#pragma unroll
        for (int k = 0; k < 4; ++k) {
            float2 d = atomLoad2(pr + 2 * k);
            cs += d.x + d.y;
        }
        cv[b * N + tid] = (tid == 0) ? 1.0f : 1.0f / cs;
        if (tid < H) {
            const float* qr = c0pB + (b * 8 + tid) * 8;
            float s = 0.0f;
#pragma unroll
            for (int k = 0; k < 4; ++k) {
                float2 d = atomLoad2(qr + 2 * k);
                s += d.x + d.y;
            }
            c0v[b * H + tid] = 1.0f / s;
        }
    }
}

// 8 independent float4s per thread. CACHED input loads (harvest L3 residency left
// by the fused build's read); non-temporal stores (no-allocate, keep input resident).
__global__ __launch_bounds__(256) void k_final(const float* __restrict__ in,
                                               const float* __restrict__ rv,
                                               const float* __restrict__ r0v,
                                               const float* __restrict__ cv,
                                               const float* __restrict__ c0v,
                                               float* __restrict__ out) {
    const size_t v0 = (size_t)blockIdx.x * 2048 + threadIdx.x;
    float4 x[8];
#pragma unroll
    for (int s = 0; s < 8; ++s)
        x[s] = reinterpret_cast<const float4*>(in)[v0 + (size_t)s * 256];
#pragma unroll
    for (int s = 0; s < 8; ++s) {
        const size_t v = v0 + (size_t)s * 256;   // float4 index
        const int j4 = (int)(v & 127);
        size_t rest = v >> 7;
        const int i = (int)(rest & 511); rest >>= 9;
        const int h = (int)(rest & 7);
        const int b = (int)(rest >> 3);
        const float R = (i == 0) ? r0v[b * H + h] : rv[b * N + i];
        float4 cl = reinterpret_cast<const float4*>(cv + b * N)[j4];
        if (j4 == 0) cl.x = c0v[b * H + h];
        f32x4 o;
        o.x = __expf(x[s].x) * R * cl.x;
        o.y = __expf(x[s].y) * R * cl.y;
        o.z = __expf(x[s].z) * R * cl.z;
        o.w = __expf(x[s].w) * R * cl.w;
        __builtin_nontemporal_store(o, reinterpret_cast<f32x4*>(out) + v);
    }
}

extern "C" void kernel_launch(void* const* d_in, const int* in_sizes, int n_in,
                              void* d_out, int out_size, void* d_ws, size_t ws_size,
                              hipStream_t stream) {
    (void)in_sizes; (void)n_in; (void)out_size; (void)ws_size;
    const float* in = (const float*)d_in[0];
    float* out = (float*)d_out;
    float* ws = (float*)d_ws;

    // persistent factor vectors (must survive into k_final) live in ws
    float* rv  = ws;           // B*N
    float* cv  = ws + 16384;   // B*N
    float* r0v = ws + 32768;   // B*H
    float* c0v = ws + 33024;   // B*H
    int* counters = (int*)(ws + 33280);  // 32 groups x 16 ints

    // partial buffers live in the tail of d_out (consumed before k_final writes)
    float* pA  = out + OFF_PA;    // B*N*8 (transposed)
    float* pB  = out + OFF_PB;    // B*N*8
    float* c0A = out + OFF_C0A;   // B*8*8
    float* c0B = out + OFF_C0B;   // B*8*8

    k_zero<<<1, 512, 0, stream>>>(counters);

    void* args[] = {(void*)&in, (void*)&pA, (void*)&pB, (void*)&c0A, (void*)&c0B,
                    (void*)&rv, (void*)&r0v, (void*)&cv, (void*)&c0v, (void*)&counters};
    hipLaunchCooperativeKernel(reinterpret_cast<void*>(k_coopb), dim3(NBLK), dim3(TPB),
                               args, 0, stream);

    k_final<<<8192, 256, 0, stream>>>(in, rv, r0v, cv, c0v, out);
}

// Round 18
// 182.573 us; speedup vs baseline: 1.0028x; 1.0028x over previous
//
#include <hip/hip_runtime.h>
#include <hip/hip_cooperative_groups.h>
#include <math.h>

#define B 32
#define H 8
#define N 512
#define NBLK 256   // cooperative blocks (1 per CU)
#define TPB 512
#define RPB 64     // G rows per cooperative block

typedef float f32x4 __attribute__((ext_vector_type(4)));  // ok for nontemporal builtins

// Cross-block data moves through relaxed agent-scope atomics (sc-bit,
// coherence-point accesses). No fences -> no L2 writeback/invalidate storms.
__device__ __forceinline__ float atomLoad(const float* p) {
    return __hip_atomic_load(p, __ATOMIC_RELAXED, __HIP_MEMORY_SCOPE_AGENT);
}
__device__ __forceinline__ float2 atomLoad2(const float* p) {
    unsigned long long u = __hip_atomic_load(
        reinterpret_cast<const unsigned long long*>(p),
        __ATOMIC_RELAXED, __HIP_MEMORY_SCOPE_AGENT);
    union { unsigned long long u; float2 f; } cvt; cvt.u = u;
    return cvt.f;
}
__device__ __forceinline__ void atomStore(float* p, float v) {
    __hip_atomic_store(p, v, __ATOMIC_RELAXED, __HIP_MEMORY_SCOPE_AGENT);
}

// 8-block (one b-group) barrier. __syncthreads() drains vmcnt for every wave,
// so all sc-bit data stores are globally visible before the signal.
__device__ __forceinline__ void group_barrier(int* cnt, int target) {
    __syncthreads();
    if (threadIdx.x == 0) {
        __hip_atomic_fetch_add(cnt, 1, __ATOMIC_RELAXED, __HIP_MEMORY_SCOPE_AGENT);
        while (__hip_atomic_load(cnt, __ATOMIC_RELAXED, __HIP_MEMORY_SCOPE_AGENT) < target)
            __builtin_amdgcn_s_sleep(1);
    }
    __syncthreads();
}

// Zero the group-barrier counters (ws is poisoned 0xAA before timing).
__global__ void k_zero(int* __restrict__ counters) {
    counters[threadIdx.x] = 0;
}

// FULLY FUSED: build + 5x(row,col) normalization + output streaming, one kernel.
// Block (b,g) owns G rows [g*64, g*64+64). Register-lean throughout (no spill).
// Output stream uses NT stores so the L3-resident input (read 30us earlier by
// this very block) is not evicted; reads are therefore largely L3 hits.
// All scratch (partials, r0 exchange) lives in ws — d_out is written only by
// the final stream. Sum orders match the split version -> same numerics.
__global__ __launch_bounds__(TPB) void k_coopb(const float* __restrict__ in,
                                               float* __restrict__ out,
                                               float* __restrict__ partA,
                                               float* __restrict__ partB,
                                               float* __restrict__ c0pA,
                                               float* __restrict__ c0pB,
                                               float* __restrict__ r0g,
                                               int* __restrict__ counters) {
    __shared__ float Gs[RPB][N];   // 128 KB
    __shared__ float E0g[N];       // exp(x[b, g, 0, :]) (head h=g row-0 slice)
    __shared__ float vec[N];       // c values
    __shared__ float EcS[H][RPB];  // exp(x[b, h, rbase+il, 0])
    __shared__ float rloc[RPB];
    __shared__ float c0rec[H];
    __shared__ float r0s[H];
    __shared__ float r0loc_s;

    const int blk = blockIdx.x;
    const int b = blk >> 3;
    const int g = blk & 7;
    const int rbase = g * RPB;
    const bool owner = (g == 0);
    const int tid = threadIdx.x;
    const int w = tid >> 6, lane = tid & 63;
    int* cnt = counters + b * 16;

    // ---- build phase: G rows straight from input into LDS (8-deep MLP) ----
    const int il4 = tid >> 7;      // 0..3
    const int j4 = tid & 127;      // float4 column index
    const size_t inb = (size_t)b * H * N * N;
    for (int c = 0; c < 16; ++c) {
        const int il = c * 4 + il4;
        const float* rowbase = in + inb + (size_t)(rbase + il) * N + j4 * 4;
        float4 xv[8];
#pragma unroll
        for (int h = 0; h < H; ++h)
            xv[h] = *reinterpret_cast<const float4*>(rowbase + (size_t)h * N * N);
        float4 acc = make_float4(0.f, 0.f, 0.f, 0.f);
#pragma unroll
        for (int h = 0; h < H; ++h) {
            float4 e;
            e.x = __expf(xv[h].x); e.y = __expf(xv[h].y);
            e.z = __expf(xv[h].z); e.w = __expf(xv[h].w);
            acc.x += e.x; acc.y += e.y; acc.z += e.z; acc.w += e.w;
            if (j4 == 0) EcS[h][il] = e.x;
        }
        *reinterpret_cast<float4*>(&Gs[il][j4 * 4]) = acc;
    }
    if (tid < 128) {   // E0g: exp of row (b, g, 0, :)
        const float4 xr = *reinterpret_cast<const float4*>(in + inb + (size_t)g * N * N + tid * 4);
        E0g[tid * 4 + 0] = __expf(xr.x);
        E0g[tid * 4 + 1] = __expf(xr.y);
        E0g[tid * 4 + 2] = __expf(xr.z);
        E0g[tid * 4 + 3] = __expf(xr.w);
    }
    __syncthreads();
    const float E00g = E0g[0];     // exp(x[b, g, 0, 0])

    for (int it = 0; it < 5; ++it) {
        // ---------- recompute c factors from transposed partials ----------
        if (it == 0) {
            vec[tid] = (tid == 0) ? 0.0f : 1.0f;  // c = 1; j=0 handled via c0 term
            if (tid < H) c0rec[tid] = 1.0f;
        } else {
            const float* pr = (it & 1) ? partB : partA;
            pr += ((size_t)b * N + tid) * 8;
            float cs = 0.0f;
#pragma unroll
            for (int k = 0; k < 4; ++k) {
                float2 d = atomLoad2(pr + 2 * k);
                cs += d.x + d.y;
            }
            vec[tid] = (tid == 0) ? 0.0f : 1.0f / cs;
            if (tid < H) {
                const float* qr = (it & 1) ? c0pB : c0pA;
                qr += (b * 8 + tid) * 8;
                float s = 0.0f;
#pragma unroll
                for (int k = 0; k < 4; ++k) {
                    float2 d = atomLoad2(qr + 2 * k);
                    s += d.x + d.y;
                }
                c0rec[tid] = 1.0f / s;
            }
        }
        __syncthreads();
        float cj[8];
#pragma unroll
        for (int k = 0; k < 8; ++k) cj[k] = vec[lane + 64 * k];
#pragma unroll
        for (int r8 = 0; r8 < 8; ++r8) {
            const int il = w * 8 + r8;
            float pacc = 0.0f;
#pragma unroll
            for (int k = 0; k < 8; ++k) pacc += Gs[il][lane + 64 * k] * cj[k];
#pragma unroll
            for (int s = 32; s > 0; s >>= 1) pacc += __shfl_down(pacc, s, 64);
            if (lane == 0) {
                float s2 = pacc;
#pragma unroll
                for (int h = 0; h < H; ++h) s2 += EcS[h][il] * c0rec[h];
                rloc[il] = 1.0f / s2;           // garbage for owner il=0, masked in stream
            }
        }
        if (w == g) {   // r0 for head h=g
            float pacc = 0.0f;
#pragma unroll
            for (int k = 0; k < 8; ++k) pacc += E0g[lane + 64 * k] * cj[k];
#pragma unroll
            for (int s = 32; s > 0; s >>= 1) pacc += __shfl_down(pacc, s, 64);
            if (lane == 0) {
                float v = 1.0f / (pacc + E00g * c0rec[g]);
                r0loc_s = v;
                if (it == 4) atomStore(r0g + b * 8 + g, v);  // publish final r0
            }
        }
        __syncthreads();
        // ---------- col phase: partial column sums (transposed store) ----------
        {
            float* pw = ((it + 1) & 1) ? partB : partA;
            float* qw = ((it + 1) & 1) ? c0pB : c0pA;
            const float r0l = r0loc_s;
            float acc2 = 0.0f;
            const int il0 = owner ? 1 : 0;  // global row 0 handled via E0 terms
#pragma unroll 8
            for (int il = il0; il < RPB; ++il) acc2 += Gs[il][tid] * rloc[il];
            acc2 += E0g[tid] * r0l;         // head g's i=0 contribution
            atomStore(&pw[((size_t)b * N + tid) * 8 + g], acc2);
            float q = EcS[w][lane] * ((owner && lane == 0) ? 0.0f : rloc[lane]);
            if (w == g && lane == 0) q += E00g * r0l;
#pragma unroll
            for (int s = 32; s > 0; s >>= 1) q += __shfl_down(q, s, 64);
            if (lane == 0) atomStore(&qw[(b * 8 + w) * 8 + g], q);
        }
        group_barrier(cnt, (it + 1) * 8);
    }

    // ---- every block: final c factors + r0 values (ws scratch, never re-written) ----
    {
        const float* pr = partB + ((size_t)b * N + tid) * 8;   // (4+1)&1 == 1
        float cs = 0.0f;
#pragma unroll
        for (int k = 0; k < 4; ++k) {
            float2 d = atomLoad2(pr + 2 * k);
            cs += d.x + d.y;
        }
        vec[tid] = (tid == 0) ? 1.0f : 1.0f / cs;   // vec[0] patched per-head below
        if (tid < H) {
            const float* qr = c0pB + (b * 8 + tid) * 8;
            float s = 0.0f;
#pragma unroll
            for (int k = 0; k < 4; ++k) {
                float2 d = atomLoad2(qr + 2 * k);
                s += d.x + d.y;
            }
            c0rec[tid] = 1.0f / s;
            r0s[tid] = atomLoad(r0g + b * 8 + tid);
        }
    }
    __syncthreads();

    // ---- final stream: out = exp(x) * R_i * C_j over own 64 rows, all heads ----
    // Input re-read is L3-warm (this block read the same bytes ~30us ago); NT
    // stores keep it that way. 8 loads in flight per iteration, ~45 VGPR.
    for (int c = 0; c < 16; ++c) {
        const int il = c * 4 + il4;
        const int gi = rbase + il;          // global row index
        const float rl = rloc[il];
        const size_t rowoff = inb + (size_t)gi * N + j4 * 4;
        const float4 c4 = *reinterpret_cast<const float4*>(&vec[j4 * 4]);
        float4 xv[8];
#pragma unroll
        for (int h = 0; h < H; ++h)
            xv[h] = *reinterpret_cast<const float4*>(in + rowoff + (size_t)h * N * N);
#pragma unroll
        for (int h = 0; h < H; ++h) {
            const float R = (gi == 0) ? r0s[h] : rl;
            const float cx = (j4 == 0) ? c0rec[h] : c4.x;
            f32x4 o;
            o.x = __expf(xv[h].x) * R * cx;
            o.y = __expf(xv[h].y) * R * c4.y;
            o.z = __expf(xv[h].z) * R * c4.z;
            o.w = __expf(xv[h].w) * R * c4.w;
            __builtin_nontemporal_store(
                o, reinterpret_cast<f32x4*>(out + rowoff + (size_t)h * N * N));
        }
    }
}

extern "C" void kernel_launch(void* const* d_in, const int* in_sizes, int n_in,
                              void* d_out, int out_size, void* d_ws, size_t ws_size,
                              hipStream_t stream) {
    (void)in_sizes; (void)n_in; (void)out_size; (void)ws_size;
    const float* in = (const float*)d_in[0];
    float* out = (float*)d_out;
    float* ws = (float*)d_ws;

    // ws layout: counters[512 ints] | pA | pB | c0A | c0B | r0g  (~1.04 MB)
    int* counters = (int*)ws;            // 32 groups x 16 ints
    float* pA  = ws + 512;               // B*N*8 (transposed partials)
    float* pB  = pA + B * N * 8;         // B*N*8
    float* c0A = pB + B * N * 8;         // B*8*8
    float* c0B = c0A + B * 8 * 8;        // B*8*8
    float* r0g = c0B + B * 8 * 8;        // B*8 final r0 exchange

    k_zero<<<1, 512, 0, stream>>>(counters);

    void* args[] = {(void*)&in, (void*)&out, (void*)&pA, (void*)&pB,
                    (void*)&c0A, (void*)&c0B, (void*)&r0g, (void*)&counters};
    hipLaunchCooperativeKernel(reinterpret_cast<void*>(k_coopb), dim3(NBLK), dim3(TPB),
                               args, 0, stream);
}